// Round 6
// baseline (15062.564 us; speedup 1.0000x reference)
//
#include <hip/hip_runtime.h>
#include <math.h>
#include <stdint.h>

#define LOG2PI 1.8378770664093453f

typedef __attribute__((ext_vector_type(8))) short bf8;   // 8 bf16
typedef __attribute__((ext_vector_type(4))) float f4;

__device__ __constant__ float ADc[6][5] = {
    {0.f,0.f,0.f,0.f,0.f},
    {0.2f,0.f,0.f,0.f,0.f},
    {0.075f,0.225f,0.f,0.f,0.f},
    {0.9777777778f,-3.7333333333f,3.5555555556f,0.f,0.f},
    {2.9525986893f,-11.5957933340f,9.8228928855f,-0.2908093278f,0.f},
    {2.8462752526f,-10.7575757576f,8.9064227177f,0.2784090909f,-0.2735313036f}};
__device__ __constant__ float CDc[6] = {0.f,0.2f,0.3f,0.8f,0.8888888889f,1.f};
__device__ __constant__ float Bcc[6] = {0.0911458333f,0.f,0.4492362983f,
    0.6510416667f,-0.3223761792f,0.1309523810f};

__device__ __forceinline__ short f2bf(float f) {
    uint32_t u = __float_as_uint(f);
    u += 0x7fffu + ((u >> 16) & 1u);          // RNE
    return (short)(u >> 16);
}
__device__ __forceinline__ float bf2f(unsigned short u) {
    return __uint_as_float(((uint32_t)u) << 16);
}
__device__ __forceinline__ float unpk(const uint32_t* p, int e) {
    uint32_t u = p[e >> 1];
    return bf2f((unsigned short)((e & 1) ? (u >> 16) : (u & 0xffff)));
}
__device__ __forceinline__ void gload16(const void* g, void* l) {
    __builtin_amdgcn_global_load_lds(
        (const __attribute__((address_space(1))) uint32_t*)(uintptr_t)g,
        (__attribute__((address_space(3))) uint32_t*)(uintptr_t)l, 16, 0, 0);
}

// ---------------------------------------------------------------------------
// Persistent FFJORD integrator. One block = 32 rows, ALL 60 stages in-kernel.
// Fragment layout (shared by phase B, phase D P-part, vbuf, th1, x):
//   e = nt*8 + mt*4 + r  (nt<4, mt<2, r<4)
//   row = m0 + mt*16 + (lane>>4)*4 + r ; hcol = wave*64 + nt*16 + (lane&15)
// Registers: Pcur f32[32], xacc f32[32], th/wt/vbuf packed bf16.
// P_k in HBM, thread-permuted: Pk[j][(block*512+tid)*32 + e] (16B coalesced).
// LDS: [64 rows][512] bf16 a1|ta1 (a2 overlays rows 0..31) + Lrow[32].
// ---------------------------------------------------------------------------
template<int FLOW>
__global__ __launch_bounds__(512, 2) void persist_k(
    const float* __restrict__ Pcur0,   // [B][512] f32
    const short* __restrict__ th1b,    // [B][512] bf16
    const short* __restrict__ vbufb,   // [B][512] bf16
    const float* __restrict__ x0g,     // voxel [B][504] / energy [B][45]
    const float* __restrict__ wtp,     // t-row of W1, f32 [512]
    const float* __restrict__ b2,      // [512]
    const float* __restrict__ b3,      // [D]
    const float* __restrict__ b31,     // [512]
    const short* __restrict__ w2t,     // [512][512]  (B^T)
    const short* __restrict__ w3c,     // [(DPAD+512)][512] (W3^T | W31^T)
    short* __restrict__ Pk,            // 5 * 8192*512 bf16, permuted
    float* __restrict__ accG)
{
    constexpr int DPAD = (FLOW == 0) ? 512 : 64;
    constexpr int DT   = (FLOW == 0) ? 504 : 45;
    __shared__ char lds[65536];
    __shared__ float Lrow[32];
    const int tid = threadIdx.x, wave = tid >> 6, lane = tid & 63;
    const int lr = lane >> 4, lc = lane & 15;
    const int m0 = blockIdx.x * 32;
    const size_t pbase = ((size_t)(blockIdx.x * 512 + tid)) << 5;
    const size_t pkstr = (size_t)8192 * 512;

    // ---------------- prologue: load persistent state ----------------
    float pc[32], xacc[32];
    uint32_t thp[16], wtk[16], vbp[16];
    float b2r[4], b31r[4], b3r[4];
    {
        unsigned short ts[32], ws[32], vs[32];
        #pragma unroll
        for (int nt = 0; nt < 4; ++nt) {
            int hc = (wave << 6) + (nt << 4) + lc;
            b2r[nt]  = b2[hc];
            b31r[nt] = b31[hc];
            #pragma unroll
            for (int mt = 0; mt < 2; ++mt)
                #pragma unroll
                for (int r = 0; r < 4; ++r) {
                    int e = nt * 8 + mt * 4 + r;
                    size_t grow = (size_t)(m0 + mt * 16 + lr * 4 + r);
                    pc[e] = Pcur0[(grow << 9) + hc];
                    ts[e] = (unsigned short)th1b[(grow << 9) + hc];
                    vs[e] = (unsigned short)vbufb[(grow << 9) + hc];
                    ws[e] = (unsigned short)f2bf(wtp[hc]);
                    if (FLOW == 0) {
                        xacc[e] = (hc < DT) ? x0g[grow * DT + hc] : 0.f;
                    }
                }
            if (FLOW == 0) b3r[nt] = (hc < DT) ? b3[hc] : 0.f;
        }
        if (FLOW == 1) {
            int xc = (wave << 4) + lc;
            b3r[0] = (wave < 4 && xc < DT) ? b3[xc] : 0.f;
            #pragma unroll
            for (int mt = 0; mt < 2; ++mt)
                #pragma unroll
                for (int r = 0; r < 4; ++r) {
                    int e = mt * 4 + r;
                    size_t grow = (size_t)(m0 + mt * 16 + lr * 4 + r);
                    xacc[e] = (wave < 4 && xc < DT) ? x0g[grow * DT + xc] : 0.f;
                }
        }
        #pragma unroll
        for (int k = 0; k < 16; ++k) {
            thp[k] = (uint32_t)ts[2*k] | ((uint32_t)ts[2*k+1] << 16);
            wtk[k] = (uint32_t)ws[2*k] | ((uint32_t)ws[2*k+1] << 16);
            vbp[k] = (uint32_t)vs[2*k] | ((uint32_t)vs[2*k+1] << 16);
        }
    }
    if (tid < 32) Lrow[tid] = 0.f;

    const float db0 = -0.1f * Bcc[0], db2 = -0.1f * Bcc[2],
                db3c = -0.1f * Bcc[3], db4 = -0.1f * Bcc[4],
                db5 = -0.1f * Bcc[5];

    // ---------------- stage loop ----------------
    for (int st = 0; st < 60; ++st) {
        const int s = st / 6, i = st - s * 6;
        const float ti = 1.f - 0.1f * (float)s - 0.1f * CDc[i];
        const float tcoef = -0.1f * Bcc[i];     // 0 for i==1
        const bool doTan = (i != 1);
        float cj[5];
        #pragma unroll
        for (int j = 0; j < 5; ++j) cj[j] = -0.1f * ADc[i][j];

        // ---- Phase B: pre1 -> tanh -> a1/ta1 to LDS ----
        #pragma unroll
        for (int g = 0; g < 4; ++g) {
            float pre[8];
            #pragma unroll
            for (int e8 = 0; e8 < 8; ++e8)
                pre[e8] = fmaf(ti, unpk(wtk, g * 8 + e8), pc[g * 8 + e8]);
            #pragma unroll
            for (int j = 0; j < 5; ++j) {
                if (j < i) {
                    bf8 v = ((const bf8*)(Pk + (size_t)j * pkstr + pbase))[g];
                    #pragma unroll
                    for (int e8 = 0; e8 < 8; ++e8)
                        pre[e8] = fmaf(cj[j], bf2f((unsigned short)v[e8]), pre[e8]);
                }
            }
            int colb = ((wave << 6) + (g << 4) + lc) << 1;
            #pragma unroll
            for (int e8 = 0; e8 < 8; ++e8) {
                int mt = e8 >> 2, r = e8 & 3;
                int lrow = (mt << 4) + (lr << 2) + r;
                int addr = (lrow << 10) + (colb ^ ((lrow & 7) << 4));
                float a = tanhf(pre[e8]);
                *(short*)(lds + addr) = f2bf(a);
                if (doTan)
                    *(short*)(lds + 32768 + addr) =
                        f2bf((1.f - a * a) * unpk(thp, g * 8 + e8));
            }
        }
        __syncthreads();

        // ---- Phase C: [a1;ta1] @ W2 ----
        f4 acc[4][4];
        #pragma unroll
        for (int mt = 0; mt < 4; ++mt)
            #pragma unroll
            for (int nt = 0; nt < 4; ++nt) acc[mt][nt] = (f4)0.0f;
        {
            const short* wb = w2t + ((size_t)((wave << 6) + lc) << 9) + (lr << 3);
            bf8 bc[4], bn[4];
            #pragma unroll
            for (int nt = 0; nt < 4; ++nt) bc[nt] = *(const bf8*)(wb + (nt << 13));
            for (int kt = 0; kt < 16; ++kt) {
                bf8 af[4];
                int kb = (kt << 6) + (lr << 4);
                #pragma unroll
                for (int mt = 0; mt < 4; ++mt) {
                    if (mt >= 2 && !doTan) continue;
                    int row = (mt << 4) + lc;
                    af[mt] = *(const bf8*)(lds + (row << 10) + (kb ^ ((row & 7) << 4)));
                }
                if (kt < 15) {
                    #pragma unroll
                    for (int nt = 0; nt < 4; ++nt)
                        bn[nt] = *(const bf8*)(wb + (nt << 13) + ((kt + 1) << 5));
                }
                #pragma unroll
                for (int mt = 0; mt < 4; ++mt) {
                    if (mt >= 2 && !doTan) continue;
                    #pragma unroll
                    for (int nt = 0; nt < 4; ++nt)
                        acc[mt][nt] = __builtin_amdgcn_mfma_f32_16x16x32_bf16(
                            af[mt], bc[nt], acc[mt][nt], 0, 0, 0);
                }
                #pragma unroll
                for (int nt = 0; nt < 4; ++nt) bc[nt] = bn[nt];
            }
        }
        __syncthreads();   // all a1/ta1 reads done before a2 overlay

        // ---- Phase C epilogue: a2 -> LDS, trace -> Lrow ----
        {
            float trp[2][4] = {{0.f,0.f,0.f,0.f},{0.f,0.f,0.f,0.f}};
            #pragma unroll
            for (int mt = 0; mt < 2; ++mt)
                #pragma unroll
                for (int nt = 0; nt < 4; ++nt) {
                    int colb = ((wave << 6) + (nt << 4) + lc) << 1;
                    #pragma unroll
                    for (int r = 0; r < 4; ++r) {
                        int lrow = (mt << 4) + (lr << 2) + r;
                        float a = tanhf(acc[mt][nt][r] + b2r[nt]);
                        *(short*)(lds + (lrow << 10) + (colb ^ ((lrow & 7) << 4))) = f2bf(a);
                        if (doTan) {
                            int e = nt * 8 + mt * 4 + r;
                            float ta2 = (1.f - a * a) * acc[mt + 2][nt][r];
                            trp[mt][r] = fmaf(ta2, unpk(vbp, e), trp[mt][r]);
                        }
                    }
                }
            if (doTan) {
                #pragma unroll
                for (int mt = 0; mt < 2; ++mt)
                    #pragma unroll
                    for (int r = 0; r < 4; ++r) {
                        float v = trp[mt][r];
                        v += __shfl_xor(v, 1); v += __shfl_xor(v, 2);
                        v += __shfl_xor(v, 4); v += __shfl_xor(v, 8);
                        if (lc == 0)
                            atomicAdd(&Lrow[(mt << 4) + (lr << 2) + r], tcoef * v);
                    }
            }
        }
        __syncthreads();   // a2 visible to all waves

        // ---- Phase D chunk A: xacc += kcoef*(a2 @ W3 + b3) ----
        if (doTan) {
            constexpr int NA = (FLOW == 0) ? 4 : 1;
            if (FLOW == 0 || wave < 4) {
                f4 aA[2][NA];
                #pragma unroll
                for (int mt = 0; mt < 2; ++mt)
                    #pragma unroll
                    for (int nt = 0; nt < NA; ++nt) aA[mt][nt] = (f4)0.0f;
                const short* wbA = w3c +
                    ((size_t)((FLOW == 0) ? ((wave << 6) + lc) : ((wave << 4) + lc)) << 9)
                    + (lr << 3);
                bf8 bc[NA], bn[NA];
                #pragma unroll
                for (int nt = 0; nt < NA; ++nt) bc[nt] = *(const bf8*)(wbA + (nt << 13));
                for (int kt = 0; kt < 16; ++kt) {
                    bf8 af[2];
                    int kb = (kt << 6) + (lr << 4);
                    #pragma unroll
                    for (int mt = 0; mt < 2; ++mt) {
                        int row = (mt << 4) + lc;
                        af[mt] = *(const bf8*)(lds + (row << 10) + (kb ^ ((row & 7) << 4)));
                    }
                    if (kt < 15) {
                        #pragma unroll
                        for (int nt = 0; nt < NA; ++nt)
                            bn[nt] = *(const bf8*)(wbA + (nt << 13) + ((kt + 1) << 5));
                    }
                    #pragma unroll
                    for (int mt = 0; mt < 2; ++mt)
                        #pragma unroll
                        for (int nt = 0; nt < NA; ++nt)
                            aA[mt][nt] = __builtin_amdgcn_mfma_f32_16x16x32_bf16(
                                af[mt], bc[nt], aA[mt][nt], 0, 0, 0);
                    #pragma unroll
                    for (int nt = 0; nt < NA; ++nt) bc[nt] = bn[nt];
                }
                #pragma unroll
                for (int mt = 0; mt < 2; ++mt)
                    #pragma unroll
                    for (int nt = 0; nt < NA; ++nt)
                        #pragma unroll
                        for (int r = 0; r < 4; ++r) {
                            int e = nt * 8 + mt * 4 + r;
                            xacc[e] = fmaf(tcoef, aA[mt][nt][r] + b3r[nt], xacc[e]);
                        }
            }
        }

        // ---- Phase D chunk B: P_i = a2 @ W31 + b31 ----
        {
            f4 aB[2][4];
            #pragma unroll
            for (int mt = 0; mt < 2; ++mt)
                #pragma unroll
                for (int nt = 0; nt < 4; ++nt) aB[mt][nt] = (f4)0.0f;
            const short* wbB = w3c + ((size_t)(DPAD + (wave << 6) + lc) << 9) + (lr << 3);
            bf8 bc[4], bn[4];
            #pragma unroll
            for (int nt = 0; nt < 4; ++nt) bc[nt] = *(const bf8*)(wbB + (nt << 13));
            for (int kt = 0; kt < 16; ++kt) {
                bf8 af[2];
                int kb = (kt << 6) + (lr << 4);
                #pragma unroll
                for (int mt = 0; mt < 2; ++mt) {
                    int row = (mt << 4) + lc;
                    af[mt] = *(const bf8*)(lds + (row << 10) + (kb ^ ((row & 7) << 4)));
                }
                if (kt < 15) {
                    #pragma unroll
                    for (int nt = 0; nt < 4; ++nt)
                        bn[nt] = *(const bf8*)(wbB + (nt << 13) + ((kt + 1) << 5));
                }
                #pragma unroll
                for (int mt = 0; mt < 2; ++mt)
                    #pragma unroll
                    for (int nt = 0; nt < 4; ++nt)
                        aB[mt][nt] = __builtin_amdgcn_mfma_f32_16x16x32_bf16(
                            af[mt], bc[nt], aB[mt][nt], 0, 0, 0);
                #pragma unroll
                for (int nt = 0; nt < 4; ++nt) bc[nt] = bn[nt];
            }
            if (i < 5) {
                short* po = Pk + (size_t)i * pkstr + pbase;
                #pragma unroll
                for (int g = 0; g < 4; ++g) {
                    bf8 o;
                    #pragma unroll
                    for (int e8 = 0; e8 < 8; ++e8) {
                        int mt = e8 >> 2, r = e8 & 3;
                        o[e8] = f2bf(aB[mt][g][r] + b31r[g]);
                    }
                    ((bf8*)po)[g] = o;
                }
            } else {
                #pragma unroll
                for (int g = 0; g < 4; ++g) {
                    bf8 v0 = ((const bf8*)(Pk + 0 * pkstr + pbase))[g];
                    bf8 v2 = ((const bf8*)(Pk + 2 * pkstr + pbase))[g];
                    bf8 v3 = ((const bf8*)(Pk + 3 * pkstr + pbase))[g];
                    bf8 v4 = ((const bf8*)(Pk + 4 * pkstr + pbase))[g];
                    #pragma unroll
                    for (int e8 = 0; e8 < 8; ++e8) {
                        int mt = e8 >> 2, r = e8 & 3;
                        int e = g * 8 + e8;
                        float pv = aB[mt][g][r] + b31r[g];
                        float pn = pc[e];
                        pn = fmaf(db0, bf2f((unsigned short)v0[e8]), pn);
                        pn = fmaf(db2, bf2f((unsigned short)v2[e8]), pn);
                        pn = fmaf(db3c, bf2f((unsigned short)v3[e8]), pn);
                        pn = fmaf(db4, bf2f((unsigned short)v4[e8]), pn);
                        pn = fmaf(db5, pv, pn);
                        pc[e] = pn;
                    }
                }
            }
        }
        __syncthreads();   // protect LDS before next stage's phase B
    }

    // ---------------- final: block-local logp reduction ----------------
    float zz = 0.f;
    if (FLOW == 0) {
        #pragma unroll
        for (int e = 0; e < 32; ++e) zz = fmaf(xacc[e], xacc[e], zz);
    } else {
        #pragma unroll
        for (int e = 0; e < 8; ++e) zz = fmaf(xacc[e], xacc[e], zz);
    }
    zz += __shfl_xor(zz, 1);  zz += __shfl_xor(zz, 2);
    zz += __shfl_xor(zz, 4);  zz += __shfl_xor(zz, 8);
    zz += __shfl_xor(zz, 16); zz += __shfl_xor(zz, 32);
    float* red = (float*)lds;
    if (lane == 0) red[wave] = zz;
    __syncthreads();
    if (tid == 0) {
        float tot = 0.f;
        #pragma unroll
        for (int w = 0; w < 8; ++w) tot += red[w];
        float ls = 0.f;
        #pragma unroll
        for (int r = 0; r < 32; ++r) ls += Lrow[r];
        atomicAdd(accG, -0.5f * tot + ls - 16.0f * (float)DT * LOG2PI);
    }
}

// ---------------------------------------------------------------------------
// bf16 MFMA GEMM (precomputes): out(M x 512) = A(M x K) @ Bt(512 x K)^T + bias
// OUT 0: f32 store; OUT 1: bf16 store. K%64==0, M%128==0, grid (4, M/128).
// ---------------------------------------------------------------------------
template<int OUT>
__global__ __launch_bounds__(256) void mgemm0(
    const short* __restrict__ A, const short* __restrict__ Bt, int K,
    float* __restrict__ Cf, short* __restrict__ Cb,
    const float* __restrict__ bias)
{
    __shared__ char lds[32768];
    const int tid = threadIdx.x, wave = tid >> 6, lane = tid & 63;
    const int m0 = blockIdx.y * 128, n0 = blockIdx.x * 128;
    const int wr = wave >> 1, wc = wave & 1;

    f4 acc[4][4];
    #pragma unroll
    for (int m = 0; m < 4; ++m)
        #pragma unroll
        for (int n = 0; n < 4; ++n) acc[m][n] = (f4)0.0f;

    const int cbs  = (((lane & 7) ^ (lane >> 3)) << 4);
    const int lrow = lane >> 3;

    for (int k0 = 0; k0 < K; k0 += 64) {
        __syncthreads();
        #pragma unroll
        for (int i = 0; i < 4; ++i) {
            int q = wave * 4 + i;
            int row = q * 8 + lrow;
            gload16((const char*)(A  + (size_t)(m0 + row) * K + k0) + cbs, lds + q * 1024);
            gload16((const char*)(Bt + (size_t)(n0 + row) * K + k0) + cbs, lds + 16384 + q * 1024);
        }
        __syncthreads();
        #pragma unroll
        for (int kk = 0; kk < 2; ++kk) {
            bf8 af[4], bfr[4];
            #pragma unroll
            for (int m = 0; m < 4; ++m) {
                int row = wr * 64 + m * 16 + (lane & 15);
                int cb  = (((lane >> 4) << 4) + (kk << 6)) ^ ((row & 7) << 4);
                af[m] = *(const bf8*)(lds + row * 128 + cb);
            }
            #pragma unroll
            for (int n = 0; n < 4; ++n) {
                int row = wc * 64 + n * 16 + (lane & 15);
                int cb  = (((lane >> 4) << 4) + (kk << 6)) ^ ((row & 7) << 4);
                bfr[n] = *(const bf8*)(lds + 16384 + row * 128 + cb);
            }
            #pragma unroll
            for (int m = 0; m < 4; ++m)
                #pragma unroll
                for (int n = 0; n < 4; ++n)
                    acc[m][n] = __builtin_amdgcn_mfma_f32_16x16x32_bf16(
                        af[m], bfr[n], acc[m][n], 0, 0, 0);
        }
    }

    #pragma unroll
    for (int m = 0; m < 4; ++m)
        #pragma unroll
        for (int r = 0; r < 4; ++r) {
            int grow = m0 + wr * 64 + m * 16 + (lane >> 4) * 4 + r;
            #pragma unroll
            for (int n = 0; n < 4; ++n) {
                int gcol = n0 + wc * 64 + n * 16 + (lane & 15);
                float v = acc[m][n][r];
                if (bias) v += bias[gcol];
                if constexpr (OUT == 0) Cf[(size_t)grow * 512 + gcol] = v;
                else                    Cb[(size_t)grow * 512 + gcol] = f2bf(v);
            }
        }
}

// ---------------------------------------------------------------------------
// prep kernels
// ---------------------------------------------------------------------------
__global__ __launch_bounds__(256) void buildw1x(
    short* __restrict__ out, const float* __restrict__ W1,
    int D, int Dpad, int Kext, int extN, int rowE, int rowC, int total)
{
    int i = blockIdx.x * 256 + threadIdx.x;
    if (i >= total) return;
    int n = i / Kext, k = i - n * Kext;
    float v = 0.f;
    if (k < D) v = W1[(size_t)k * 512 + n];
    else if (k >= Dpad) {
        int j = k - Dpad;
        if (j < extN)       v = W1[(size_t)(rowE + j) * 512 + n];
        else if (j == extN) v = W1[(size_t)rowC * 512 + n];
    }
    out[i] = f2bf(v);
}

__global__ __launch_bounds__(256) void buildab(
    short* __restrict__ out, const float* __restrict__ x,
    const float* __restrict__ e, const float* __restrict__ c,
    int D, int Dpad, int Kext, int extN, int total)
{
    int i = blockIdx.x * 256 + threadIdx.x;
    if (i >= total) return;
    int b = i / Kext, k = i - b * Kext;
    float v = 0.f;
    if (k < D) v = x[(size_t)b * D + k];
    else if (k >= Dpad) {
        int j = k - Dpad;
        if (e && j < extN)       v = e[(size_t)b * 45 + j];
        else if (c && j == extN) v = c[b];
    }
    out[i] = f2bf(v);
}

__global__ __launch_bounds__(256) void padbf(
    short* __restrict__ out, const float* __restrict__ in,
    int K, int Kpad, int total)
{
    int i = blockIdx.x * 256 + threadIdx.x;
    if (i >= total) return;
    int n = i / Kpad, k = i - n * Kpad;
    out[i] = (k < K) ? f2bf(in[(size_t)n * K + k]) : (short)0;
}

__global__ __launch_bounds__(256) void convtrans(
    short* __restrict__ out, const float* __restrict__ in,
    int K, int N, int Kpad, int total)
{
    int i = blockIdx.x * 256 + threadIdx.x;
    if (i >= total) return;
    int n = i / Kpad, k = i - n * Kpad;
    out[i] = (k < K && n < N) ? f2bf(in[(size_t)k * N + n]) : (short)0;
}

__global__ __launch_bounds__(256) void padvec(
    float* __restrict__ out, const float* __restrict__ in, int N, int Npad)
{
    int i = blockIdx.x * 256 + threadIdx.x;
    if (i < Npad) out[i] = (i < N) ? in[i] : 0.f;
}

// b31[n] = sum_d b3[d]*W1[d][n] ; one block per n
__global__ __launch_bounds__(256) void b31k(
    float* __restrict__ b31, const float* __restrict__ b3,
    const float* __restrict__ W1, int D)
{
    __shared__ float ps[4];
    int n = blockIdx.x;
    int lane = threadIdx.x & 63, wave = threadIdx.x >> 6;
    float s = 0.f;
    for (int d = threadIdx.x; d < D; d += 256)
        s = fmaf(b3[d], W1[(size_t)d * 512 + n], s);
    #pragma unroll
    for (int off = 32; off; off >>= 1) s += __shfl_down(s, off, 64);
    if (lane == 0) ps[wave] = s;
    __syncthreads();
    if (threadIdx.x == 0) b31[n] = ps[0] + ps[1] + ps[2] + ps[3];
}

__global__ void finalize_k(float* __restrict__ out, const float* __restrict__ acc)
{
    out[0] = -(acc[0] + acc[1]) * (1.f / 8192.f);
}

// ---------------------------------------------------------------------------
extern "C" void kernel_launch(void* const* d_in, const int* in_sizes, int n_in,
                              void* d_out, int out_size, void* d_ws, size_t ws_size,
                              hipStream_t stream)
{
    (void)in_sizes; (void)n_in; (void)out_size; (void)ws_size;
    const float* voxel  = (const float*)d_in[0];
    const float* energy = (const float*)d_in[1];
    const float* cond   = (const float*)d_in[2];
    const float* eps_v  = (const float*)d_in[3];
    const float* eps_e  = (const float*)d_in[4];
    const float* Wt[2][5] = {
        {(const float*)d_in[5], (const float*)d_in[6], (const float*)d_in[7], (const float*)d_in[8], (const float*)d_in[9]},
        {(const float*)d_in[11],(const float*)d_in[12],(const float*)d_in[13],(const float*)d_in[14],(const float*)d_in[15]}};
    const float* b3t[2] = {(const float*)d_in[10], (const float*)d_in[16]};

    const int Bn = 8192, H = 512;
    const size_t BH = (size_t)Bn * H;

    char* wp = (char*)d_ws;
    auto alloc = [&](size_t bytes) { char* p = wp; wp += (bytes + 255) & ~(size_t)255; return p; };
    float* Pcur0 = (float*)alloc(BH * 4);
    short* th1b  = (short*)alloc(BH * 2);
    short* vbufb = (short*)alloc(BH * 2);
    short* Pk    = (short*)alloc(5 * BH * 2);      // permuted
    short* abx   = (short*)alloc((size_t)Bn * 576 * 2);
    short* abeps = (short*)alloc((size_t)Bn * 576 * 2);
    short* w1x   = (short*)alloc((size_t)512 * 576 * 2);
    short* w2t   = (short*)alloc((size_t)512 * 512 * 2);
    short* w3bt  = (short*)alloc((size_t)512 * 576 * 2);
    short* w3c   = (short*)alloc((size_t)1088 * 512 * 2);
    float* w31f  = (float*)alloc((size_t)512 * 512 * 4);
    float* b31   = (float*)alloc(512 * 4);
    float* acc   = (float*)alloc(256);

    (void)hipMemsetAsync(acc, 0, 2 * sizeof(float), stream);

    for (int flow = 0; flow < 2; ++flow) {
        const int D    = (flow == 0) ? 504 : 45;
        const int Dpad = (flow == 0) ? 512 : 64;
        const int Kext = Dpad + 64;              // 576 / 128
        const int extN = (flow == 0) ? 45 : 0;
        const int rowE = (flow == 0) ? 505 : 0;
        const int rowC = (flow == 0) ? 550 : 46;
        const float* x_in = (flow == 0) ? voxel : energy;
        const float* eps  = (flow == 0) ? eps_v : eps_e;
        const float* ecnd = (flow == 0) ? energy : nullptr;
        const float* W1 = Wt[flow][0]; const float* b1 = Wt[flow][1];
        const float* W2 = Wt[flow][2]; const float* b2 = Wt[flow][3];
        const float* W3 = Wt[flow][4]; const float* b3 = b3t[flow];
        const float* wtp = W1 + (size_t)D * H;    // t-row of W1

        // ---- prep
        buildw1x<<<(512 * Kext + 255) / 256, 256, 0, stream>>>(
            w1x, W1, D, Dpad, Kext, extN, rowE, rowC, 512 * Kext);
        buildab<<<(Bn * Kext + 255) / 256, 256, 0, stream>>>(
            abx, x_in, ecnd, cond, D, Dpad, Kext, extN, Bn * Kext);
        buildab<<<(Bn * Kext + 255) / 256, 256, 0, stream>>>(
            abeps, eps, nullptr, nullptr, D, Dpad, Kext, extN, Bn * Kext);
        padbf<<<(512 * Kext + 255) / 256, 256, 0, stream>>>(w3bt, W3, D, Kext, 512 * Kext);
        convtrans<<<(512 * 512 + 255) / 256, 256, 0, stream>>>(w2t, W2, 512, 512, 512, 512 * 512);
        mgemm0<0><<<dim3(4, 4), 256, 0, stream>>>(w3bt, w1x, Kext, w31f, nullptr, nullptr);
        convtrans<<<(Dpad * 512 + 255) / 256, 256, 0, stream>>>(w3c, W3, 512, D, 512, Dpad * 512);
        convtrans<<<(512 * 512 + 255) / 256, 256, 0, stream>>>(
            w3c + (size_t)Dpad * 512, w31f, 512, 512, 512, 512 * 512);
        b31k<<<512, 256, 0, stream>>>(b31, b3, W1, D);

        mgemm0<0><<<dim3(4, 64), 256, 0, stream>>>(abx, w1x, Kext, Pcur0, nullptr, b1);
        mgemm0<1><<<dim3(4, 64), 256, 0, stream>>>(abeps, w1x, Kext, nullptr, th1b, nullptr);
        mgemm0<1><<<dim3(4, 64), 256, 0, stream>>>(abeps, w3bt, Kext, nullptr, vbufb, nullptr);

        // ---- persistent integration (all 60 stages)
        if (flow == 0)
            persist_k<0><<<256, 512, 0, stream>>>(Pcur0, th1b, vbufb, x_in, wtp,
                b2, b3, b31, w2t, w3c, Pk, acc + 0);
        else
            persist_k<1><<<256, 512, 0, stream>>>(Pcur0, th1b, vbufb, x_in, wtp,
                b2, b3, b31, w2t, w3c, Pk, acc + 1);
    }
    finalize_k<<<1, 1, 0, stream>>>((float*)d_out, acc);
}